// Round 4
// baseline (267.469 us; speedup 1.0000x reference)
//
#include <hip/hip_runtime.h>

typedef unsigned short u16;
typedef __bf16 bf16x8 __attribute__((ext_vector_type(8)));
typedef float    f32x4 __attribute__((ext_vector_type(4)));
typedef unsigned short u16x8 __attribute__((ext_vector_type(8)));

__device__ __forceinline__ float bf2f(u16 v){ return __uint_as_float(((unsigned int)v) << 16); }
__device__ __forceinline__ u16 f2bf(float f){
    unsigned int u = __float_as_uint(f);
    u += 0x7fffu + ((u >> 16) & 1u);
    return (u16)(u >> 16);
}
// truncating bf16 (~2^-8 rel err, rounds toward zero); selects d16_hi stores
__device__ __forceinline__ u16 f2bf_t(float f){ return (u16)(__float_as_uint(f) >> 16); }
// pack hi16 of two floats: result = [lo.hi16, hi.hi16]
__device__ __forceinline__ unsigned pack_trunc(float hi, float lo){
    return __builtin_amdgcn_perm(__float_as_uint(hi), __float_as_uint(lo), 0x07060302);
}
// raw v_exp_f32 (no libm denorm fixup); x=-1e30 -> 0
__device__ __forceinline__ float exp2_fast(float x){
    float r; asm("v_exp_f32 %0, %1" : "=v"(r) : "v"(x)); return r;
}

// async global->LDS, 16B per lane; LDS dest = wave-uniform base + lane*16.
__device__ __forceinline__ void glds16(const u16* gp, u16* lp){
    __builtin_amdgcn_global_load_lds((unsigned int __attribute__((address_space(1)))*)gp,
                                     (unsigned int __attribute__((address_space(3)))*)lp,
                                     16, 0, 0);
}

// Wave-uniform input-dtype probe (verified R4-R7).
__device__ __forceinline__ int probe_f32(const u16* __restrict__ xp){
    u16 lo = xp[2 * (threadIdx.x & 63)];
    int e = (lo >> 7) & 0xff;
    bool bad = !(e == 0 || (e > 96 && e < 160));
    return __popcll(__ballot(bad)) > 16;
}

// ---------- x -> canonical bf16 (into d_out scratch) ----------
__global__ __launch_bounds__(256) void conv_x(const void* __restrict__ src, u16* __restrict__ dst,
                                              const u16* __restrict__ xprobe){
    const int isf32 = probe_f32(xprobe);
    size_t i = ((size_t)blockIdx.x * 256 + threadIdx.x) * 8;
    if (isf32){
        const float* p = (const float*)src + i;
        float4 a = *(const float4*)p, b = *(const float4*)(p + 4);
        u16x8 o = { f2bf(a.x), f2bf(a.y), f2bf(a.z), f2bf(a.w),
                    f2bf(b.x), f2bf(b.y), f2bf(b.z), f2bf(b.w) };
        *(u16x8*)(dst + i) = o;
    } else {
        *(u16x8*)(dst + i) = *(const u16x8*)((const u16*)src + i);
    }
}

// ---------- transpose+convert: out[C][R](bf16) = in[R][C](f32 or bf16) ----------
__global__ __launch_bounds__(256) void transposeW(const void* __restrict__ in, u16* __restrict__ out,
                                                  int R, int C, const u16* __restrict__ xprobe){
    __shared__ u16 t[64][65];
    const int isf32 = probe_f32(xprobe);
    const int c0 = blockIdx.x * 64, r0 = blockIdx.y * 64;
    const int tx = threadIdx.x & 15, ty = threadIdx.x >> 4;
#pragma unroll
    for (int i = 0; i < 4; i++){
        int r = ty + i * 16;
        u16 a, b, c, d;
        if (isf32){
            float4 v = *(const float4*)((const float*)in + (size_t)(r0 + r) * C + c0 + tx * 4);
            a = f2bf(v.x); b = f2bf(v.y); c = f2bf(v.z); d = f2bf(v.w);
        } else {
            ushort4 v = *(const ushort4*)((const u16*)in + (size_t)(r0 + r) * C + c0 + tx * 4);
            a = v.x; b = v.y; c = v.z; d = v.w;
        }
        t[r][tx*4+0] = a; t[r][tx*4+1] = b; t[r][tx*4+2] = c; t[r][tx*4+3] = d;
    }
    __syncthreads();
#pragma unroll
    for (int i = 0; i < 4; i++){
        int oc = ty + i * 16;
        ushort4 v;
        v.x = t[tx*4+0][oc]; v.y = t[tx*4+1][oc]; v.z = t[tx*4+2][oc]; v.w = t[tx*4+3][oc];
        *(ushort4*)(out + (size_t)(c0 + oc) * R + r0 + tx * 4) = v;
    }
}

// ---------------- GEMM 256x256 tile, BK=32, 4-slot deep pipeline ----------------
// C[M,N] = A[M,K] @ Bt[N,K]^T + bias.  512 threads = 8 waves (2 Mx4 N), wave tile 128x64.
// LDS: 4 slots x (A 256x32 + B 256x32) bf16 = 128 KiB.  Prefetch distance: 3 K-tiles.
// R4: m201-faithful phase shape. Per phase:
//   { ds_read this phase's fragments ; stage one half ; [vmcnt ladder] ;
//     s_barrier ; s_waitcnt lgkmcnt(0) ; sched_barrier ; setprio(1) ; 16 MFMA ;
//     setprio(0) ; s_barrier }
// In-phase lgkm waits give each wave a DIFFERENT stall duration at barrier release
// -> cross-wave MFMA/LDS pipe overlap (T5's role-split), which R3's lockstep killed.
// Counted vmcnt once per K-tile (end of phase 1): WAITV(8) retires tile t+1; tail 4->0.
// LDS chunk swizzle: 16B chunk c of row r at c ^ ((r>>1)&3), pre-swizzled global source.
// MODE 0: epilogue scatters Q(pre-scaled)/K -> [bh][t][64], V -> Vt[bh][d][2048].
// MODE 1: C row-major, f32 or bf16 per probe.
// Requires K % 32 == 0 and K/32 >= 4, M % 256 == 0, N % 256 == 0, grid count % 8 == 0.
#define BAR()    asm volatile("s_barrier" ::: "memory")
#define WAITV(n) asm volatile("s_waitcnt vmcnt(" #n ")" ::: "memory")
#define WAITL0() asm volatile("s_waitcnt lgkmcnt(0)" ::: "memory")

template<int MODE>
__global__ __launch_bounds__(512, 2) void gemm256(
    const u16* __restrict__ A, const u16* __restrict__ Bt, const void* __restrict__ bias,
    void* __restrict__ C, u16* __restrict__ Cq, u16* __restrict__ Ck, u16* __restrict__ Cv,
    const u16* __restrict__ xprobe, int M, int N, int K)
{
    __shared__ u16 lds[65536];           // 128 KiB, reused by the epilogue restage
    const int isf32 = probe_f32(xprobe);
    const int tid = threadIdx.x;
    const int wave = tid >> 6, lane = tid & 63;
    const int quad = lane >> 4, ml = lane & 15;
    const int wm = wave >> 2, wn = wave & 3;

    // XCD-aware bijective block swizzle (nwg % 8 == 0 for both dispatches)
    const int nbx = gridDim.x;
    int flat = blockIdx.y * nbx + blockIdx.x;
    const int cpx = (nbx * gridDim.y) >> 3;
    flat = (flat & 7) * cpx + (flat >> 3);
    const int m_blk = (flat / nbx) * 256;
    const int n_blk = (flat % nbx) * 256;

    // ---- staging precompute: thread -> (row, 16B chunk) of a 256x32 tile ----
    const int rowb = tid >> 2;                       // 0..127 (load i adds i*128)
    const int swz  = (tid & 3) ^ ((tid >> 3) & 3);   // pre-swizzled source chunk
    const u16* a0 = A  + (size_t)(m_blk + rowb) * K + swz * 8;
    const u16* a1 = a0 + (size_t)128 * K;
    const u16* b0 = Bt + (size_t)(n_blk + rowb) * K + swz * 8;
    const u16* b1 = b0 + (size_t)128 * K;
    u16* ldA = lds + wave * 512;                     // + slot*16384 + i*4096
    u16* ldB = lds + 8192 + wave * 512;

    // ---- fragment read offsets (swizzled, conflict-free) ----
    const int fsw  = (quad ^ ((ml >> 1) & 3)) * 8;
    const int aoff = (wm * 128 + ml) * 32 + fsw;     // + mt*512
    const int boff = (wn * 64  + ml) * 32 + fsw;     // + nt*512 (within B region +8192)

    f32x4 acc[8][4];
#pragma unroll
    for (int a = 0; a < 8; a++)
#pragma unroll
        for (int b = 0; b < 4; b++)
            acc[a][b] = (f32x4){0.f, 0.f, 0.f, 0.f};

    const int T = K >> 5;

#define STAGE_A(t) { const int s_ = ((t) & 3) * 16384; const size_t ko_ = (size_t)(t) * 32; \
    glds16(a0 + ko_, ldA + s_); glds16(a1 + ko_, ldA + s_ + 4096); }
#define STAGE_B(t) { const int s_ = ((t) & 3) * 16384; const size_t ko_ = (size_t)(t) * 32; \
    glds16(b0 + ko_, ldB + s_); glds16(b1 + ko_, ldB + s_ + 4096); }

    // prologue: tiles 0..2 in flight (12 loads); wait to 8 -> tile 0 complete
    STAGE_A(0); STAGE_B(0); STAGE_A(1); STAGE_B(1); STAGE_A(2); STAGE_B(2);
    WAITV(8);
    BAR();

    for (int t = 0; t < T; ++t){
        const u16* Ls = lds + (t & 3) * 16384;
        bf16x8 fa[4], fb[4];
        // ---- phase 0: read A-half0 + B frags | stage A(t+3) | bar | lgkm0 | MFMA ----
#pragma unroll
        for (int i = 0; i < 4; i++)    fa[i] = *(const bf16x8*)&Ls[aoff + i * 512];
#pragma unroll
        for (int nt = 0; nt < 4; nt++) fb[nt] = *(const bf16x8*)&Ls[8192 + boff + nt * 512];
        if (t + 3 < T) STAGE_A(t + 3);
        BAR();
        WAITL0();
        __builtin_amdgcn_sched_barrier(0);
        __builtin_amdgcn_s_setprio(1);
#pragma unroll
        for (int i = 0; i < 4; i++)
#pragma unroll
            for (int nt = 0; nt < 4; nt++)
                acc[i][nt] = __builtin_amdgcn_mfma_f32_16x16x32_bf16(fa[i], fb[nt], acc[i][nt], 0, 0, 0);
        __builtin_amdgcn_s_setprio(0);
        BAR();
        // ---- phase 1: read A-half1 | stage B(t+3) | ladder | bar | lgkm0 | MFMA ----
#pragma unroll
        for (int i = 0; i < 4; i++)    fa[i] = *(const bf16x8*)&Ls[aoff + (4 + i) * 512];
        if (t + 3 < T) STAGE_B(t + 3);
        // counted wait: tile t+1 complete behind the barrier (tail: 4 -> 0)
        if (t < T - 3)       { WAITV(8); }
        else if (t == T - 3) { WAITV(4); }
        else                 { WAITV(0); }
        BAR();
        WAITL0();
        __builtin_amdgcn_sched_barrier(0);
        __builtin_amdgcn_s_setprio(1);
#pragma unroll
        for (int i = 0; i < 4; i++)
#pragma unroll
            for (int nt = 0; nt < 4; nt++)
                acc[4 + i][nt] = __builtin_amdgcn_mfma_f32_16x16x32_bf16(fa[i], fb[nt], acc[4 + i][nt], 0, 0, 0);
        __builtin_amdgcn_s_setprio(0);
        BAR();
    }
#undef STAGE_A
#undef STAGE_B

    const float QSC = 0.18033688f;   // 0.125 * log2(e) folded into Q
    if (MODE == 0){
        __syncthreads();             // full drain; epilogue reuses lds
        const int which = n_blk >> 10;
        const int hbase = (n_blk >> 6) & 15;
        const int b = m_blk >> 11, t0 = m_blk & 2047;
        if (which < 2){
            const float sc = (which == 0) ? QSC : 1.0f;
            u16* dst0 = (which == 0) ? Cq : Ck;
            u16* Ct = lds;                        // [256][136]
#pragma unroll
            for (int hn = 0; hn < 2; hn++){       // two 128-col half-passes
                if ((wn >> 1) == hn){
#pragma unroll
                    for (int nt = 0; nt < 4; nt++){
                        int col = (wn & 1) * 64 + nt * 16 + ml;
                        int gc  = n_blk + hn * 128 + col;
                        float bv = isf32 ? ((const float*)bias)[gc] : bf2f(((const u16*)bias)[gc]);
#pragma unroll
                        for (int mt = 0; mt < 8; mt++){
                            int row0 = wm * 128 + mt * 16 + quad * 4;
#pragma unroll
                            for (int r = 0; r < 4; r++)
                                Ct[(row0 + r) * 136 + col] = f2bf_t((acc[mt][nt][r] + bv) * sc);
                        }
                    }
                }
                __syncthreads();
#pragma unroll
                for (int i = 0; i < 8; i++){
                    int u = i * 512 + tid;
                    int row = u >> 4, c8 = u & 15;
                    int h = hbase + hn * 2 + (c8 >> 3), d8 = (c8 & 7) * 8;
                    u16x8 v = *(const u16x8*)&Ct[row * 136 + c8 * 8];
                    *(u16x8*)&dst0[(((size_t)(b * 16 + h)) * 2048 + (t0 + row)) * 64 + d8] = v;
                }
                __syncthreads();
            }
        } else {
            u16* Ct = lds;                        // [128 cols][264 rows] (transposed)
#pragma unroll
            for (int hn = 0; hn < 2; hn++){
                if ((wn >> 1) == hn){
#pragma unroll
                    for (int nt = 0; nt < 4; nt++){
                        int col = (wn & 1) * 64 + nt * 16 + ml;
                        int gc  = n_blk + hn * 128 + col;
                        float bv = isf32 ? ((const float*)bias)[gc] : bf2f(((const u16*)bias)[gc]);
#pragma unroll
                        for (int mt = 0; mt < 8; mt++){
                            int row0 = wm * 128 + mt * 16 + quad * 4;
                            uint2 pk;
                            pk.x = pack_trunc(acc[mt][nt][1] + bv, acc[mt][nt][0] + bv);
                            pk.y = pack_trunc(acc[mt][nt][3] + bv, acc[mt][nt][2] + bv);
                            *(uint2*)&Ct[col * 264 + row0] = pk;
                        }
                    }
                }
                __syncthreads();
                // 128 cols x 32 chunks of 8 rows = 4096 u16x8 = 8 iters x 512 threads
#pragma unroll
                for (int i = 0; i < 8; i++){
                    int u = i * 512 + tid;
                    int col = u >> 5, c8 = u & 31;
                    int h = hbase + hn * 2 + (col >> 6), d = col & 63;
                    u16x8 v = *(const u16x8*)&Ct[col * 264 + c8 * 8];
                    *(u16x8*)&Cv[(((size_t)(b * 16 + h)) * 64 + d) * 2048 + t0 + c8 * 8] = v;
                }
                __syncthreads();
            }
        }
    } else {
#pragma unroll
        for (int nt = 0; nt < 4; nt++){
            int col = n_blk + wn * 64 + nt * 16 + ml;
            float bv = isf32 ? ((const float*)bias)[col] : bf2f(((const u16*)bias)[col]);
#pragma unroll
            for (int mt = 0; mt < 8; mt++){
                int row0 = m_blk + wm * 128 + mt * 16 + quad * 4;
                float o0 = acc[mt][nt][0] + bv, o1 = acc[mt][nt][1] + bv;
                float o2 = acc[mt][nt][2] + bv, o3 = acc[mt][nt][3] + bv;
                if (isf32){
                    float* p = (float*)C + (size_t)row0 * N + col;
                    p[0] = o0; p[N] = o1; p[2*N] = o2; p[3*N] = o3;
                } else {
                    u16* p = (u16*)C + (size_t)row0 * N + col;
                    p[0] = f2bf(o0); p[N] = f2bf(o1); p[2*N] = f2bf(o2); p[3*N] = f2bf(o3);
                }
            }
        }
    }
}

// ---------------- flash attention, causal, hd=64, T=2048 ----------------
// R6 structure (transient s-regs, ONE P round-trip per tile, VGPR ~116) +
// R7's VALU cuts only (raw v_exp_f32, truncating d16 P-stores).
#define PS 136
__global__ __launch_bounds__(256) void attn_kernel(
    const u16* __restrict__ Q, const u16* __restrict__ K, const u16* __restrict__ Vt,
    u16* __restrict__ Y)
{
    __shared__ u16 Ksm[128 * 64];        // K[t'][c], chunk c stored at c ^ (t'&7)
    __shared__ u16 Vsm[64 * 128];        // V^T[d][t'], chunk c stored at c ^ (d&15)
    __shared__ u16 Psm[4][32 * PS];      // per-wave P (2 m-tiles x 16 rows), padded

    const int tid = threadIdx.x, wave = tid >> 6, lane = tid & 63;
    const int quad = lane >> 4, ml = lane & 15;
    const int flat = blockIdx.x;
    const int qb = 15 - (flat >> 6);
    const int rest = flat & 63;
    const int bh = ((rest & 7) << 3) | (rest >> 3);
    const int q0 = qb * 128;
    const size_t base = (size_t)bh * (2048 * 64);
    const float NEG = -1.0e30f;

    bf16x8 qf[2][2];
#pragma unroll
    for (int mt = 0; mt < 2; mt++)
#pragma unroll
        for (int ks = 0; ks < 2; ks++)
            qf[mt][ks] = *(const bf16x8*)(Q + base + (size_t)(q0 + mt * 64 + wave * 16 + ml) * 64 + ks * 32 + quad * 8);

    f32x4 acc[2][4];
#pragma unroll
    for (int mt = 0; mt < 2; mt++)
#pragma unroll
        for (int nt = 0; nt < 4; nt++) acc[mt][nt] = (f32x4){0.f, 0.f, 0.f, 0.f};
    float l[2][4];
#pragma unroll
    for (int mt = 0; mt < 2; mt++)
#pragma unroll
        for (int r = 0; r < 4; r++) l[mt][r] = 0.f;

    const int ntj = qb + 1;
    for (int j = 0; j < ntj; j++){
        const int j0 = j * 128;
        __syncthreads();
#pragma unroll
        for (int i = 0; i < 4; i++){
            int ub = i * 256 + wave * 64;
            int u = ub + lane;
            int row = u >> 3, cg = (lane & 7) ^ (row & 7);
            glds16(K + base + (size_t)(j0 + row) * 64 + cg * 8, Ksm + ub * 8);
            int d = u >> 4, vg = (lane & 15) ^ (d & 15);
            glds16(Vt + base + (size_t)d * 2048 + j0 + vg * 8, Vsm + ub * 8);
        }
        __syncthreads();
        const bool lastj = (j == ntj - 1);

        // S = Q@K^T per 16-col tile; exp2 + P write immediately (s regs transient)
#pragma unroll
        for (int nt = 0; nt < 8; nt++){
            bf16x8 bk0 = *(const bf16x8*)&Ksm[(nt * 16 + ml) * 64 + ((quad)     ^ (ml & 7)) * 8];
            bf16x8 bk1 = *(const bf16x8*)&Ksm[(nt * 16 + ml) * 64 + ((4 + quad) ^ (ml & 7)) * 8];
            f32x4 z = {0.f, 0.f, 0.f, 0.f};
            f32x4 s0 = __builtin_amdgcn_mfma_f32_16x16x32_bf16(qf[0][0], bk0, z, 0, 0, 0);
            s0 = __builtin_amdgcn_mfma_f32_16x16x32_bf16(qf[0][1], bk1, s0, 0, 0, 0);
            f32x4 s1 = __builtin_amdgcn_mfma_f32_16x16x32_bf16(qf[1][0], bk0, z, 0, 0, 0);
            s1 = __builtin_amdgcn_mfma_f32_16x16x32_bf16(qf[1][1], bk1, s1, 0, 0, 0);
            if (lastj){
                int cl = nt * 16 + ml;
                int r0 = wave * 16 + quad * 4;
#pragma unroll
                for (int r = 0; r < 4; r++){
                    if (cl > r0 + r)      s0[r] = NEG;
                    if (cl > 64 + r0 + r) s1[r] = NEG;
                }
            }
#pragma unroll
            for (int r = 0; r < 4; r++){
                float p0 = exp2_fast(s0[r]); l[0][r] += p0;
                Psm[wave][(quad * 4 + r) * PS + nt * 16 + ml] = f2bf_t(p0);
                float p1 = exp2_fast(s1[r]); l[1][r] += p1;
                Psm[wave][(16 + quad * 4 + r) * PS + nt * 16 + ml] = f2bf_t(p1);
            }
        }
        // O += P @ V  (vf shared across both m-tiles)
#pragma unroll
        for (int ks = 0; ks < 4; ks++){
            bf16x8 pf0 = *(const bf16x8*)&Psm[wave][ml * PS + ks * 32 + quad * 8];
            bf16x8 pf1 = *(const bf16x8*)&Psm[wave][(16 + ml) * PS + ks * 32 + quad * 8];
#pragma unroll
            for (int nt = 0; nt < 4; nt++){
                bf16x8 vf = *(const bf16x8*)&Vsm[(nt * 16 + ml) * 128 + (((ks * 4 + quad) ^ ml) & 15) * 8];
                acc[0][nt] = __builtin_amdgcn_mfma_f32_16x16x32_bf16(pf0, vf, acc[0][nt], 0, 0, 0);
                acc[1][nt] = __builtin_amdgcn_mfma_f32_16x16x32_bf16(pf1, vf, acc[1][nt], 0, 0, 0);
            }
        }
    }
    // epilogue: l-reduction across the 16 ml lanes, then scale + store
    const int b = bh >> 4, h = bh & 15;
#pragma unroll
    for (int mt = 0; mt < 2; mt++){
        f32x4 inv;
#pragma unroll
        for (int r = 0; r < 4; r++){
            float t = l[mt][r];
            t += __shfl_xor(t, 1, 64);
            t += __shfl_xor(t, 2, 64);
            t += __shfl_xor(t, 4, 64);
            t += __shfl_xor(t, 8, 64);
            inv[r] = 1.0f / t;
        }
#pragma unroll
        for (int nt = 0; nt < 4; nt++)
#pragma unroll
            for (int r = 0; r < 4; r++){
                size_t row = (size_t)b * 2048 + q0 + mt * 64 + wave * 16 + quad * 4 + r;
                Y[row * 1024 + h * 64 + nt * 16 + ml] = f2bf(acc[mt][nt][r] * inv[r]);
            }
    }
}

extern "C" void kernel_launch(void* const* d_in, const int* in_sizes, int n_in,
                              void* d_out, int out_size, void* d_ws, size_t ws_size,
                              hipStream_t stream) {
    const void* x      = d_in[0];   // [8192][1024]  f32 or bf16 (probed at runtime)
    const void* W_attn = d_in[1];   // [1024][3072]
    const void* b_attn = d_in[2];   // [3072]
    const void* W_proj = d_in[3];   // [1024][1024]
    const void* b_proj = d_in[4];   // [1024]
    const u16* xprobe = (const u16*)x;

    // ws layout (64 MB, sequential reuse — verified R4-R7):
    //   [0, 8M)  elems: Q (pre-scaled); reused for Wt_proj after attention
    //   [8M,16M) elems: K
    //   [16M,24M)elems: Vt  [bh][d][t]
    //   [24M,32M)elems: Wt_attn (3M) -> Yw (8M)
    // x-as-bf16 lives in d_out as scratch until the final GEMM.
    u16* ws = (u16*)d_ws;
    u16* Qw = ws;
    u16* Kw = ws + 8u * 1024 * 1024;
    u16* Vw = ws + 16u * 1024 * 1024;
    u16* R  = ws + 24u * 1024 * 1024;
    u16* Wt_attn = R;
    u16* Yw      = R;
    u16* Wt_proj = Qw;
    u16* xb = (u16*)d_out;

    conv_x<<<4096, 256, 0, stream>>>(x, xb, xprobe);
    transposeW<<<dim3(48, 16), 256, 0, stream>>>(W_attn, Wt_attn, 1024, 3072, xprobe);
    gemm256<0><<<dim3(12, 32), 512, 0, stream>>>(
        xb, Wt_attn, b_attn, nullptr, Qw, Kw, Vw, xprobe, 8192, 3072, 1024);
    attn_kernel<<<1024, 256, 0, stream>>>(Qw, Kw, Vw, Yw);
    transposeW<<<dim3(16, 16), 256, 0, stream>>>(W_proj, Wt_proj, 1024, 1024, xprobe);
    gemm256<1><<<dim3(4, 32), 512, 0, stream>>>(
        Yw, Wt_proj, b_proj, d_out, nullptr, nullptr, nullptr, xprobe, 8192, 1024, 1024);
}

// Round 5
// 251.493 us; speedup vs baseline: 1.0635x; 1.0635x over previous
//
#include <hip/hip_runtime.h>

typedef unsigned short u16;
typedef __bf16 bf16x8 __attribute__((ext_vector_type(8)));
typedef float    f32x4 __attribute__((ext_vector_type(4)));
typedef unsigned short u16x8 __attribute__((ext_vector_type(8)));

__device__ __forceinline__ float bf2f(u16 v){ return __uint_as_float(((unsigned int)v) << 16); }
__device__ __forceinline__ u16 f2bf(float f){
    unsigned int u = __float_as_uint(f);
    u += 0x7fffu + ((u >> 16) & 1u);
    return (u16)(u >> 16);
}
// truncating bf16 (~2^-8 rel err, rounds toward zero); selects d16_hi stores
__device__ __forceinline__ u16 f2bf_t(float f){ return (u16)(__float_as_uint(f) >> 16); }
// pack hi16 of two floats: result = [lo.hi16, hi.hi16]
__device__ __forceinline__ unsigned pack_trunc(float hi, float lo){
    return __builtin_amdgcn_perm(__float_as_uint(hi), __float_as_uint(lo), 0x07060302);
}
// raw v_exp_f32 (no libm denorm fixup); x=-1e30 -> 0
__device__ __forceinline__ float exp2_fast(float x){
    float r; asm("v_exp_f32 %0, %1" : "=v"(r) : "v"(x)); return r;
}

// async global->LDS, 16B per lane; LDS dest = wave-uniform base + lane*16.
__device__ __forceinline__ void glds16(const u16* gp, u16* lp){
    __builtin_amdgcn_global_load_lds((unsigned int __attribute__((address_space(1)))*)gp,
                                     (unsigned int __attribute__((address_space(3)))*)lp,
                                     16, 0, 0);
}

// Wave-uniform input-dtype probe (verified R4-R7).
__device__ __forceinline__ int probe_f32(const u16* __restrict__ xp){
    u16 lo = xp[2 * (threadIdx.x & 63)];
    int e = (lo >> 7) & 0xff;
    bool bad = !(e == 0 || (e > 96 && e < 160));
    return __popcll(__ballot(bad)) > 16;
}

// ---------- x -> canonical bf16 (into d_out scratch) ----------
__global__ __launch_bounds__(256) void conv_x(const void* __restrict__ src, u16* __restrict__ dst,
                                              const u16* __restrict__ xprobe){
    const int isf32 = probe_f32(xprobe);
    size_t i = ((size_t)blockIdx.x * 256 + threadIdx.x) * 8;
    if (isf32){
        const float* p = (const float*)src + i;
        float4 a = *(const float4*)p, b = *(const float4*)(p + 4);
        u16x8 o = { f2bf(a.x), f2bf(a.y), f2bf(a.z), f2bf(a.w),
                    f2bf(b.x), f2bf(b.y), f2bf(b.z), f2bf(b.w) };
        *(u16x8*)(dst + i) = o;
    } else {
        *(u16x8*)(dst + i) = *(const u16x8*)((const u16*)src + i);
    }
}

// ---------- transpose+convert: out[C][R](bf16) = in[R][C](f32 or bf16) ----------
__global__ __launch_bounds__(256) void transposeW(const void* __restrict__ in, u16* __restrict__ out,
                                                  int R, int C, const u16* __restrict__ xprobe){
    __shared__ u16 t[64][65];
    const int isf32 = probe_f32(xprobe);
    const int c0 = blockIdx.x * 64, r0 = blockIdx.y * 64;
    const int tx = threadIdx.x & 15, ty = threadIdx.x >> 4;
#pragma unroll
    for (int i = 0; i < 4; i++){
        int r = ty + i * 16;
        u16 a, b, c, d;
        if (isf32){
            float4 v = *(const float4*)((const float*)in + (size_t)(r0 + r) * C + c0 + tx * 4);
            a = f2bf(v.x); b = f2bf(v.y); c = f2bf(v.z); d = f2bf(v.w);
        } else {
            ushort4 v = *(const ushort4*)((const u16*)in + (size_t)(r0 + r) * C + c0 + tx * 4);
            a = v.x; b = v.y; c = v.z; d = v.w;
        }
        t[r][tx*4+0] = a; t[r][tx*4+1] = b; t[r][tx*4+2] = c; t[r][tx*4+3] = d;
    }
    __syncthreads();
#pragma unroll
    for (int i = 0; i < 4; i++){
        int oc = ty + i * 16;
        ushort4 v;
        v.x = t[tx*4+0][oc]; v.y = t[tx*4+1][oc]; v.z = t[tx*4+2][oc]; v.w = t[tx*4+3][oc];
        *(ushort4*)(out + (size_t)(c0 + oc) * R + r0 + tx * 4) = v;
    }
}

// ---------------- GEMM (m97 structure, BK=64): C[M,N] = A[M,K] @ Bt[N,K]^T + bias --------
// 256 threads = 4 waves (2Mx2N), wave tile 64x64, tile 128x128, single-buffered staging.
// R5 upgrades over the proven R0 kernel (attn/conv/transpose untouched):
//  - BK=64: halves barrier/drain events per K (16 iters, 32 MFMA per drain).
//  - LDS union: staging (32 KiB) and epilogue Ct (34 KiB) share one 34 KiB array
//    -> 4 blocks/CU co-resident (was 3) for cross-block MFMA/mem overlap (m114).
//  - bank swizzle on the 128B-row staging: chunk ^= (row&7), pre-swizzled GLOBAL
//    source + linear LDS dest (rule #21); read side applies the same XOR.
//    This is the attn-Ksm-proven pattern (conflict-free at identical geometry).
//  - T1 bijective XCD swizzle on the block id (grid counts % 8 == 0).
// MODE 0: LDS-restaged epilogue -> coalesced 16B stores to Q(pre-scaled)/K ([bh][t][64])
//         and Vt ([bh][d][2048], V-blocks transposed in LDS).
// MODE 1: C row-major, f32 or bf16 per probe.
#define CTS 136
template<int MODE>
__global__ __launch_bounds__(256) void gemm128(
    const u16* __restrict__ A, const u16* __restrict__ Bt, const void* __restrict__ bias,
    void* __restrict__ C, u16* __restrict__ Cq, u16* __restrict__ Ck, u16* __restrict__ Cv,
    const u16* __restrict__ xprobe, int M, int N, int K)
{
    __shared__ u16 lds[17408];           // union: staging 16384 elems | Ct 128*136
    u16* Asm = lds;                      // [128][64]
    u16* Bsm = lds + 8192;               // [128][64]
    u16* Ct  = lds;                      // epilogue restage (after sync)
    const int isf32 = probe_f32(xprobe);
    const int tid = threadIdx.x;
    const int wave = tid >> 6, lane = tid & 63;
    const int quad = lane >> 4, ml = lane & 15;

    // T1: bijective XCD swizzle (nwg % 8 == 0 for all dispatches)
    const int nbx = gridDim.x;
    int flat = blockIdx.y * nbx + blockIdx.x;
    const int cpx = (nbx * gridDim.y) >> 3;
    flat = (flat & 7) * cpx + (flat >> 3);
    const int m_blk = (flat / nbx) * 128;
    const int n_blk = (flat % nbx) * 128;

    const int wm = (wave >> 1) * 64, wn = (wave & 1) * 64;
    const int srow = lane >> 3;          // 0..7 within the 8-row group
    const int sch  = lane & 7;           // linear dest chunk

    f32x4 acc[4][4];
#pragma unroll
    for (int a = 0; a < 4; a++)
#pragma unroll
        for (int b = 0; b < 4; b++)
            acc[a][b] = (f32x4){0.f, 0.f, 0.f, 0.f};

    for (int k0 = 0; k0 < K; k0 += 64){
        __syncthreads();
#pragma unroll
        for (int i = 0; i < 4; i++){
            int row = wave * 32 + i * 8 + srow;          // 0..127
            int sc  = sch ^ (row & 7);                   // pre-swizzled source chunk
            glds16(A  + (size_t)(m_blk + row) * K + k0 + sc * 8, Asm + (wave * 32 + i * 8) * 64);
            glds16(Bt + (size_t)(n_blk + row) * K + k0 + sc * 8, Bsm + (wave * 32 + i * 8) * 64);
        }
        __syncthreads();
#pragma unroll
        for (int ks = 0; ks < 2; ks++){
            bf16x8 af[4], bfr[4];
#pragma unroll
            for (int mt = 0; mt < 4; mt++)
                af[mt]  = *(const bf16x8*)&Asm[(wm + mt * 16 + ml) * 64 + ((ks * 4 + quad) ^ (ml & 7)) * 8];
#pragma unroll
            for (int nt = 0; nt < 4; nt++)
                bfr[nt] = *(const bf16x8*)&Bsm[(wn + nt * 16 + ml) * 64 + ((ks * 4 + quad) ^ (ml & 7)) * 8];
#pragma unroll
            for (int mt = 0; mt < 4; mt++)
#pragma unroll
                for (int nt = 0; nt < 4; nt++)
                    acc[mt][nt] = __builtin_amdgcn_mfma_f32_16x16x32_bf16(af[mt], bfr[nt], acc[mt][nt], 0, 0, 0);
        }
    }
    __syncthreads();                      // fence: staging LDS -> Ct reuse

    const float QSC = 0.18033688f;   // 0.125 * log2(e) folded into Q
    if (MODE == 0){
        const int which = n_blk >> 10;
        const int hbase = (n_blk >> 6) & 15;
        if (which < 2){
            const float sc = (which == 0) ? QSC : 1.0f;
#pragma unroll
            for (int nt = 0; nt < 4; nt++){
                int col = wn + nt * 16 + ml;
                float bv = isf32 ? ((const float*)bias)[n_blk + col] : bf2f(((const u16*)bias)[n_blk + col]);
#pragma unroll
                for (int mt = 0; mt < 4; mt++){
                    int row0 = wm + mt * 16 + quad * 4;
#pragma unroll
                    for (int r = 0; r < 4; r++)
                        Ct[(row0 + r) * CTS + col] = f2bf_t((acc[mt][nt][r] + bv) * sc);
                }
            }
            __syncthreads();
            u16* dst0 = (which == 0) ? Cq : Ck;
            const int b = m_blk >> 11, t0 = m_blk & 2047;
#pragma unroll
            for (int i = 0; i < 8; i++){
                int u = i * 256 + tid;
                int row = u >> 4, c8 = u & 15;
                int h = hbase + (c8 >> 3), d8 = (c8 & 7) * 8;
                u16x8 v = *(const u16x8*)&Ct[row * CTS + c8 * 8];
                *(u16x8*)&dst0[(((size_t)(b * 16 + h)) * 2048 + (t0 + row)) * 64 + d8] = v;
            }
        } else {
#pragma unroll
            for (int nt = 0; nt < 4; nt++){
                int col = wn + nt * 16 + ml;
                float bv = isf32 ? ((const float*)bias)[n_blk + col] : bf2f(((const u16*)bias)[n_blk + col]);
#pragma unroll
                for (int mt = 0; mt < 4; mt++){
                    int row0 = wm + mt * 16 + quad * 4;
                    uint2 pk;
                    pk.x = pack_trunc(acc[mt][nt][1] + bv, acc[mt][nt][0] + bv);
                    pk.y = pack_trunc(acc[mt][nt][3] + bv, acc[mt][nt][2] + bv);
                    *(uint2*)&Ct[col * CTS + row0] = pk;
                }
            }
            __syncthreads();
            const int b = m_blk >> 11, t0 = m_blk & 2047;
#pragma unroll
            for (int i = 0; i < 8; i++){
                int u = i * 256 + tid;
                int col = u >> 4, c8 = u & 15;
                int h = hbase + (col >> 6), d = col & 63;
                u16x8 v = *(const u16x8*)&Ct[col * CTS + c8 * 8];
                *(u16x8*)&Cv[(((size_t)(b * 16 + h)) * 64 + d) * 2048 + t0 + c8 * 8] = v;
            }
        }
    } else {
#pragma unroll
        for (int nt = 0; nt < 4; nt++){
            int col = n_blk + wn + nt * 16 + ml;
            float bv = isf32 ? ((const float*)bias)[col] : bf2f(((const u16*)bias)[col]);
#pragma unroll
            for (int mt = 0; mt < 4; mt++){
                float o0 = acc[mt][nt][0] + bv, o1 = acc[mt][nt][1] + bv;
                float o2 = acc[mt][nt][2] + bv, o3 = acc[mt][nt][3] + bv;
                int row0 = m_blk + wm + mt * 16 + quad * 4;
                if (isf32){
                    float* p = (float*)C + (size_t)row0 * N + col;
                    p[0] = o0; p[N] = o1; p[2*N] = o2; p[3*N] = o3;
                } else {
                    u16* p = (u16*)C + (size_t)row0 * N + col;
                    p[0] = f2bf(o0); p[N] = f2bf(o1); p[2*N] = f2bf(o2); p[3*N] = f2bf(o3);
                }
            }
        }
    }
}

// ---------------- flash attention, causal, hd=64, T=2048 ----------------
// R6 structure (transient s-regs, ONE P round-trip per tile, VGPR ~116) +
// R7's VALU cuts only (raw v_exp_f32, truncating d16 P-stores).
#define PS 136
__global__ __launch_bounds__(256) void attn_kernel(
    const u16* __restrict__ Q, const u16* __restrict__ K, const u16* __restrict__ Vt,
    u16* __restrict__ Y)
{
    __shared__ u16 Ksm[128 * 64];        // K[t'][c], chunk c stored at c ^ (t'&7)
    __shared__ u16 Vsm[64 * 128];        // V^T[d][t'], chunk c stored at c ^ (d&15)
    __shared__ u16 Psm[4][32 * PS];      // per-wave P (2 m-tiles x 16 rows), padded

    const int tid = threadIdx.x, wave = tid >> 6, lane = tid & 63;
    const int quad = lane >> 4, ml = lane & 15;
    const int flat = blockIdx.x;
    const int qb = 15 - (flat >> 6);
    const int rest = flat & 63;
    const int bh = ((rest & 7) << 3) | (rest >> 3);
    const int q0 = qb * 128;
    const size_t base = (size_t)bh * (2048 * 64);
    const float NEG = -1.0e30f;

    bf16x8 qf[2][2];
#pragma unroll
    for (int mt = 0; mt < 2; mt++)
#pragma unroll
        for (int ks = 0; ks < 2; ks++)
            qf[mt][ks] = *(const bf16x8*)(Q + base + (size_t)(q0 + mt * 64 + wave * 16 + ml) * 64 + ks * 32 + quad * 8);

    f32x4 acc[2][4];
#pragma unroll
    for (int mt = 0; mt < 2; mt++)
#pragma unroll
        for (int nt = 0; nt < 4; nt++) acc[mt][nt] = (f32x4){0.f, 0.f, 0.f, 0.f};
    float l[2][4];
#pragma unroll
    for (int mt = 0; mt < 2; mt++)
#pragma unroll
        for (int r = 0; r < 4; r++) l[mt][r] = 0.f;

    const int ntj = qb + 1;
    for (int j = 0; j < ntj; j++){
        const int j0 = j * 128;
        __syncthreads();
#pragma unroll
        for (int i = 0; i < 4; i++){
            int ub = i * 256 + wave * 64;
            int u = ub + lane;
            int row = u >> 3, cg = (lane & 7) ^ (row & 7);
            glds16(K + base + (size_t)(j0 + row) * 64 + cg * 8, Ksm + ub * 8);
            int d = u >> 4, vg = (lane & 15) ^ (d & 15);
            glds16(Vt + base + (size_t)d * 2048 + j0 + vg * 8, Vsm + ub * 8);
        }
        __syncthreads();
        const bool lastj = (j == ntj - 1);

        // S = Q@K^T per 16-col tile; exp2 + P write immediately (s regs transient)
#pragma unroll
        for (int nt = 0; nt < 8; nt++){
            bf16x8 bk0 = *(const bf16x8*)&Ksm[(nt * 16 + ml) * 64 + ((quad)     ^ (ml & 7)) * 8];
            bf16x8 bk1 = *(const bf16x8*)&Ksm[(nt * 16 + ml) * 64 + ((4 + quad) ^ (ml & 7)) * 8];
            f32x4 z = {0.f, 0.f, 0.f, 0.f};
            f32x4 s0 = __builtin_amdgcn_mfma_f32_16x16x32_bf16(qf[0][0], bk0, z, 0, 0, 0);
            s0 = __builtin_amdgcn_mfma_f32_16x16x32_bf16(qf[0][1], bk1, s0, 0, 0, 0);
            f32x4 s1 = __builtin_amdgcn_mfma_f32_16x16x32_bf16(qf[1][0], bk0, z, 0, 0, 0);
            s1 = __builtin_amdgcn_mfma_f32_16x16x32_bf16(qf[1][1], bk1, s1, 0, 0, 0);
            if (lastj){
                int cl = nt * 16 + ml;
                int r0 = wave * 16 + quad * 4;
#pragma unroll
                for (int r = 0; r < 4; r++){
                    if (cl > r0 + r)      s0[r] = NEG;
                    if (cl > 64 + r0 + r) s1[r] = NEG;
                }
            }
#pragma unroll
            for (int r = 0; r < 4; r++){
                float p0 = exp2_fast(s0[r]); l[0][r] += p0;
                Psm[wave][(quad * 4 + r) * PS + nt * 16 + ml] = f2bf_t(p0);
                float p1 = exp2_fast(s1[r]); l[1][r] += p1;
                Psm[wave][(16 + quad * 4 + r) * PS + nt * 16 + ml] = f2bf_t(p1);
            }
        }
        // O += P @ V  (vf shared across both m-tiles)
#pragma unroll
        for (int ks = 0; ks < 4; ks++){
            bf16x8 pf0 = *(const bf16x8*)&Psm[wave][ml * PS + ks * 32 + quad * 8];
            bf16x8 pf1 = *(const bf16x8*)&Psm[wave][(16 + ml) * PS + ks * 32 + quad * 8];
#pragma unroll
            for (int nt = 0; nt < 4; nt++){
                bf16x8 vf = *(const bf16x8*)&Vsm[(nt * 16 + ml) * 128 + (((ks * 4 + quad) ^ ml) & 15) * 8];
                acc[0][nt] = __builtin_amdgcn_mfma_f32_16x16x32_bf16(pf0, vf, acc[0][nt], 0, 0, 0);
                acc[1][nt] = __builtin_amdgcn_mfma_f32_16x16x32_bf16(pf1, vf, acc[1][nt], 0, 0, 0);
            }
        }
    }
    // epilogue: l-reduction across the 16 ml lanes, then scale + store
    const int b = bh >> 4, h = bh & 15;
#pragma unroll
    for (int mt = 0; mt < 2; mt++){
        f32x4 inv;
#pragma unroll
        for (int r = 0; r < 4; r++){
            float t = l[mt][r];
            t += __shfl_xor(t, 1, 64);
            t += __shfl_xor(t, 2, 64);
            t += __shfl_xor(t, 4, 64);
            t += __shfl_xor(t, 8, 64);
            inv[r] = 1.0f / t;
        }
#pragma unroll
        for (int nt = 0; nt < 4; nt++)
#pragma unroll
            for (int r = 0; r < 4; r++){
                size_t row = (size_t)b * 2048 + q0 + mt * 64 + wave * 16 + quad * 4 + r;
                Y[row * 1024 + h * 64 + nt * 16 + ml] = f2bf(acc[mt][nt][r] * inv[r]);
            }
    }
}

extern "C" void kernel_launch(void* const* d_in, const int* in_sizes, int n_in,
                              void* d_out, int out_size, void* d_ws, size_t ws_size,
                              hipStream_t stream) {
    const void* x      = d_in[0];   // [8192][1024]  f32 or bf16 (probed at runtime)
    const void* W_attn = d_in[1];   // [1024][3072]
    const void* b_attn = d_in[2];   // [3072]
    const void* W_proj = d_in[3];   // [1024][1024]
    const void* b_proj = d_in[4];   // [1024]
    const u16* xprobe = (const u16*)x;

    // ws layout (64 MB, sequential reuse — verified R4-R7):
    //   [0, 8M)  elems: Q (pre-scaled); reused for Wt_proj after attention
    //   [8M,16M) elems: K
    //   [16M,24M)elems: Vt  [bh][d][t]
    //   [24M,32M)elems: Wt_attn (3M) -> Yw (8M)
    // x-as-bf16 lives in d_out as scratch until the final GEMM.
    u16* ws = (u16*)d_ws;
    u16* Qw = ws;
    u16* Kw = ws + 8u * 1024 * 1024;
    u16* Vw = ws + 16u * 1024 * 1024;
    u16* R  = ws + 24u * 1024 * 1024;
    u16* Wt_attn = R;
    u16* Yw      = R;
    u16* Wt_proj = Qw;
    u16* xb = (u16*)d_out;

    conv_x<<<4096, 256, 0, stream>>>(x, xb, xprobe);
    transposeW<<<dim3(48, 16), 256, 0, stream>>>(W_attn, Wt_attn, 1024, 3072, xprobe);
    gemm128<0><<<dim3(24, 64), 256, 0, stream>>>(
        xb, Wt_attn, b_attn, nullptr, Qw, Kw, Vw, xprobe, 8192, 3072, 1024);
    attn_kernel<<<1024, 256, 0, stream>>>(Qw, Kw, Vw, Yw);
    transposeW<<<dim3(16, 16), 256, 0, stream>>>(W_proj, Wt_proj, 1024, 1024, xprobe);
    gemm128<1><<<dim3(8, 64), 256, 0, stream>>>(
        Yw, Wt_proj, b_proj, d_out, nullptr, nullptr, nullptr, xprobe, 8192, 1024, 1024);
}

// Round 6
// 250.509 us; speedup vs baseline: 1.0677x; 1.0039x over previous
//
#include <hip/hip_runtime.h>

typedef unsigned short u16;
typedef __bf16 bf16x8 __attribute__((ext_vector_type(8)));
typedef float    f32x4 __attribute__((ext_vector_type(4)));
typedef unsigned short u16x8 __attribute__((ext_vector_type(8)));

__device__ __forceinline__ float bf2f(u16 v){ return __uint_as_float(((unsigned int)v) << 16); }
__device__ __forceinline__ u16 f2bf(float f){
    unsigned int u = __float_as_uint(f);
    u += 0x7fffu + ((u >> 16) & 1u);
    return (u16)(u >> 16);
}
// truncating bf16 (~2^-8 rel err, rounds toward zero); selects d16_hi stores
__device__ __forceinline__ u16 f2bf_t(float f){ return (u16)(__float_as_uint(f) >> 16); }
// pack hi16 of two floats: result = [lo.hi16, hi.hi16]
__device__ __forceinline__ unsigned pack_trunc(float hi, float lo){
    return __builtin_amdgcn_perm(__float_as_uint(hi), __float_as_uint(lo), 0x07060302);
}
// raw v_exp_f32 (no libm denorm fixup); x=-1e30 -> 0
__device__ __forceinline__ float exp2_fast(float x){
    float r; asm("v_exp_f32 %0, %1" : "=v"(r) : "v"(x)); return r;
}

// async global->LDS, 16B per lane; LDS dest = wave-uniform base + lane*16.
__device__ __forceinline__ void glds16(const u16* gp, u16* lp){
    __builtin_amdgcn_global_load_lds((unsigned int __attribute__((address_space(1)))*)gp,
                                     (unsigned int __attribute__((address_space(3)))*)lp,
                                     16, 0, 0);
}

// Wave-uniform input-dtype probe (verified R4-R7).
__device__ __forceinline__ int probe_f32(const u16* __restrict__ xp){
    u16 lo = xp[2 * (threadIdx.x & 63)];
    int e = (lo >> 7) & 0xff;
    bool bad = !(e == 0 || (e > 96 && e < 160));
    return __popcll(__ballot(bad)) > 16;
}

// ---------- x -> canonical bf16 (into d_out scratch) ----------
__global__ __launch_bounds__(256) void conv_x(const void* __restrict__ src, u16* __restrict__ dst,
                                              const u16* __restrict__ xprobe){
    const int isf32 = probe_f32(xprobe);
    size_t i = ((size_t)blockIdx.x * 256 + threadIdx.x) * 8;
    if (isf32){
        const float* p = (const float*)src + i;
        float4 a = *(const float4*)p, b = *(const float4*)(p + 4);
        u16x8 o = { f2bf(a.x), f2bf(a.y), f2bf(a.z), f2bf(a.w),
                    f2bf(b.x), f2bf(b.y), f2bf(b.z), f2bf(b.w) };
        *(u16x8*)(dst + i) = o;
    } else {
        *(u16x8*)(dst + i) = *(const u16x8*)((const u16*)src + i);
    }
}

// ---------- transpose+convert: out[C][R](bf16) = in[R][C](f32 or bf16) ----------
__global__ __launch_bounds__(256) void transposeW(const void* __restrict__ in, u16* __restrict__ out,
                                                  int R, int C, const u16* __restrict__ xprobe){
    __shared__ u16 t[64][65];
    const int isf32 = probe_f32(xprobe);
    const int c0 = blockIdx.x * 64, r0 = blockIdx.y * 64;
    const int tx = threadIdx.x & 15, ty = threadIdx.x >> 4;
#pragma unroll
    for (int i = 0; i < 4; i++){
        int r = ty + i * 16;
        u16 a, b, c, d;
        if (isf32){
            float4 v = *(const float4*)((const float*)in + (size_t)(r0 + r) * C + c0 + tx * 4);
            a = f2bf(v.x); b = f2bf(v.y); c = f2bf(v.z); d = f2bf(v.w);
        } else {
            ushort4 v = *(const ushort4*)((const u16*)in + (size_t)(r0 + r) * C + c0 + tx * 4);
            a = v.x; b = v.y; c = v.z; d = v.w;
        }
        t[r][tx*4+0] = a; t[r][tx*4+1] = b; t[r][tx*4+2] = c; t[r][tx*4+3] = d;
    }
    __syncthreads();
#pragma unroll
    for (int i = 0; i < 4; i++){
        int oc = ty + i * 16;
        ushort4 v;
        v.x = t[tx*4+0][oc]; v.y = t[tx*4+1][oc]; v.z = t[tx*4+2][oc]; v.w = t[tx*4+3][oc];
        *(ushort4*)(out + (size_t)(c0 + oc) * R + r0 + tx * 4) = v;
    }
}

// ---------------- GEMM 128x128, BK=32, 3-slot rotating pipeline ----------------
// C[M,N] = A[M,K] @ Bt[N,K]^T + bias. 256 threads = 4 waves (2Mx2N), wave tile 64x64.
// R6: minimum-T3 pipeline on the R5 winner.
//  - 3 LDS slots x (A[128][32] + B[128][32]) = 48 KiB (Ct epilogue unions in; 3 blocks/CU).
//  - per 16-MFMA iter: STAGE(t+2 -> free slot) | 8 ds_read(t) | MFMA | WAITV(4) | s_barrier.
//    Loads never drain to 0 in steady state (2 tiles in flight across barriers); tail 0.
//    One barrier/iter is race-free: each wave's reads retire (lgkm) before its MFMA ->
//    barrier; the overwritten slot was fully read one iteration earlier.
//  - bank swizzle for 64B rows: store chunk (l&3)^((l>>3)&3) via pre-swizzled GLOBAL
//    source (linear glds dest, rule #21); read chunk quad^((ml>>1)&3) -> 2-way (free).
//  - T1 bijective XCD swizzle (grid % 8 == 0).
// MODE 0: LDS-restaged epilogue -> coalesced 16B stores to Q(pre-scaled)/K ([bh][t][64])
//         and Vt ([bh][d][2048], V-blocks transposed in LDS).
// MODE 1: C row-major, f32 or bf16 per probe.  Requires K%32==0, K/32>=2.
#define CTS 136
#define BAR()    asm volatile("s_barrier" ::: "memory")
#define WAITV(n) asm volatile("s_waitcnt vmcnt(" #n ")" ::: "memory")

template<int MODE>
__global__ __launch_bounds__(256) void gemm128(
    const u16* __restrict__ A, const u16* __restrict__ Bt, const void* __restrict__ bias,
    void* __restrict__ C, u16* __restrict__ Cq, u16* __restrict__ Ck, u16* __restrict__ Cv,
    const u16* __restrict__ xprobe, int M, int N, int K)
{
    __shared__ u16 lds[24576];           // 3 slots x 8192 u16 | Ct 128*136 (17408) union
    u16* Ct = lds;
    const int isf32 = probe_f32(xprobe);
    WAITV(0);                            // probe load retired -> clean vmcnt baseline
    const int tid = threadIdx.x;
    const int wave = tid >> 6, lane = tid & 63;
    const int quad = lane >> 4, ml = lane & 15;

    // T1: bijective XCD swizzle (nwg % 8 == 0 for all dispatches)
    const int nbx = gridDim.x;
    int flat = blockIdx.y * nbx + blockIdx.x;
    const int cpx = (nbx * gridDim.y) >> 3;
    flat = (flat & 7) * cpx + (flat >> 3);
    const int m_blk = (flat / nbx) * 128;
    const int n_blk = (flat % nbx) * 128;

    const int wm = (wave >> 1) * 64, wn = (wave & 1) * 64;

    // staging: thread -> (row = tid>>2 [+64], chunk); source chunk pre-swizzled
    const int srow = tid >> 2;                       // 0..63
    const int csrc = (tid & 3) ^ ((tid >> 3) & 3);
    const u16* pa0 = A  + (size_t)(m_blk + srow) * K + csrc * 8;
    const u16* pa1 = pa0 + (size_t)64 * K;
    const u16* pb0 = Bt + (size_t)(n_blk + srow) * K + csrc * 8;
    const u16* pb1 = pb0 + (size_t)64 * K;

    // fragment read chunk (swizzled): 2-way bank aliasing only
    const int cread = (quad ^ ((ml >> 1) & 3)) * 8;

    u16* s0 = lds; u16* s1 = lds + 8192; u16* s2 = lds + 16384;

#define STAGE(sl, kt) { const size_t ko_ = (size_t)(kt) * 32;            \
    glds16(pa0 + ko_, (sl) + wave * 512);                                \
    glds16(pa1 + ko_, (sl) + 2048 + wave * 512);                         \
    glds16(pb0 + ko_, (sl) + 4096 + wave * 512);                         \
    glds16(pb1 + ko_, (sl) + 6144 + wave * 512); }

    f32x4 acc[4][4];
#pragma unroll
    for (int a = 0; a < 4; a++)
#pragma unroll
        for (int b = 0; b < 4; b++)
            acc[a][b] = (f32x4){0.f, 0.f, 0.f, 0.f};

    const int T = K >> 5;
    STAGE(s0, 0); STAGE(s1, 1);
    WAITV(4);
    BAR();

    for (int t = 0; t < T; ++t){
        if (t + 2 < T) STAGE(s2, t + 2);
        bf16x8 af[4], bfr[4];
#pragma unroll
        for (int mt = 0; mt < 4; mt++)
            af[mt]  = *(const bf16x8*)&s0[(wm + mt * 16 + ml) * 32 + cread];
#pragma unroll
        for (int nt = 0; nt < 4; nt++)
            bfr[nt] = *(const bf16x8*)&s0[4096 + (wn + nt * 16 + ml) * 32 + cread];
#pragma unroll
        for (int mt = 0; mt < 4; mt++)
#pragma unroll
            for (int nt = 0; nt < 4; nt++)
                acc[mt][nt] = __builtin_amdgcn_mfma_f32_16x16x32_bf16(af[mt], bfr[nt], acc[mt][nt], 0, 0, 0);
        if (t < T - 2) { WAITV(4); } else { WAITV(0); }
        BAR();
        u16* tmp = s0; s0 = s1; s1 = s2; s2 = tmp;
    }
#undef STAGE
    __syncthreads();                      // fence: staging LDS -> Ct reuse

    const float QSC = 0.18033688f;   // 0.125 * log2(e) folded into Q
    if (MODE == 0){
        const int which = n_blk >> 10;
        const int hbase = (n_blk >> 6) & 15;
        if (which < 2){
            const float sc = (which == 0) ? QSC : 1.0f;
#pragma unroll
            for (int nt = 0; nt < 4; nt++){
                int col = wn + nt * 16 + ml;
                float bv = isf32 ? ((const float*)bias)[n_blk + col] : bf2f(((const u16*)bias)[n_blk + col]);
#pragma unroll
                for (int mt = 0; mt < 4; mt++){
                    int row0 = wm + mt * 16 + quad * 4;
#pragma unroll
                    for (int r = 0; r < 4; r++)
                        Ct[(row0 + r) * CTS + col] = f2bf_t((acc[mt][nt][r] + bv) * sc);
                }
            }
            __syncthreads();
            u16* dst0 = (which == 0) ? Cq : Ck;
            const int b = m_blk >> 11, t0 = m_blk & 2047;
#pragma unroll
            for (int i = 0; i < 8; i++){
                int u = i * 256 + tid;
                int row = u >> 4, c8 = u & 15;
                int h = hbase + (c8 >> 3), d8 = (c8 & 7) * 8;
                u16x8 v = *(const u16x8*)&Ct[row * CTS + c8 * 8];
                *(u16x8*)&dst0[(((size_t)(b * 16 + h)) * 2048 + (t0 + row)) * 64 + d8] = v;
            }
        } else {
#pragma unroll
            for (int nt = 0; nt < 4; nt++){
                int col = wn + nt * 16 + ml;
                float bv = isf32 ? ((const float*)bias)[n_blk + col] : bf2f(((const u16*)bias)[n_blk + col]);
#pragma unroll
                for (int mt = 0; mt < 4; mt++){
                    int row0 = wm + mt * 16 + quad * 4;
                    uint2 pk;
                    pk.x = pack_trunc(acc[mt][nt][1] + bv, acc[mt][nt][0] + bv);
                    pk.y = pack_trunc(acc[mt][nt][3] + bv, acc[mt][nt][2] + bv);
                    *(uint2*)&Ct[col * CTS + row0] = pk;
                }
            }
            __syncthreads();
            const int b = m_blk >> 11, t0 = m_blk & 2047;
#pragma unroll
            for (int i = 0; i < 8; i++){
                int u = i * 256 + tid;
                int col = u >> 4, c8 = u & 15;
                int h = hbase + (col >> 6), d = col & 63;
                u16x8 v = *(const u16x8*)&Ct[col * CTS + c8 * 8];
                *(u16x8*)&Cv[(((size_t)(b * 16 + h)) * 64 + d) * 2048 + t0 + c8 * 8] = v;
            }
        }
    } else {
#pragma unroll
        for (int nt = 0; nt < 4; nt++){
            int col = n_blk + wn + nt * 16 + ml;
            float bv = isf32 ? ((const float*)bias)[col] : bf2f(((const u16*)bias)[col]);
#pragma unroll
            for (int mt = 0; mt < 4; mt++){
                float o0 = acc[mt][nt][0] + bv, o1 = acc[mt][nt][1] + bv;
                float o2 = acc[mt][nt][2] + bv, o3 = acc[mt][nt][3] + bv;
                int row0 = m_blk + wm + mt * 16 + quad * 4;
                if (isf32){
                    float* p = (float*)C + (size_t)row0 * N + col;
                    p[0] = o0; p[N] = o1; p[2*N] = o2; p[3*N] = o3;
                } else {
                    u16* p = (u16*)C + (size_t)row0 * N + col;
                    p[0] = f2bf(o0); p[N] = f2bf(o1); p[2*N] = f2bf(o2); p[3*N] = f2bf(o3);
                }
            }
        }
    }
}

// ---------------- flash attention, causal, hd=64, T=2048 ----------------
// R6 structure (transient s-regs, ONE P round-trip per tile, VGPR ~116) +
// R7's VALU cuts only (raw v_exp_f32, truncating d16 P-stores).
#define PS 136
__global__ __launch_bounds__(256) void attn_kernel(
    const u16* __restrict__ Q, const u16* __restrict__ K, const u16* __restrict__ Vt,
    u16* __restrict__ Y)
{
    __shared__ u16 Ksm[128 * 64];        // K[t'][c], chunk c stored at c ^ (t'&7)
    __shared__ u16 Vsm[64 * 128];        // V^T[d][t'], chunk c stored at c ^ (d&15)
    __shared__ u16 Psm[4][32 * PS];      // per-wave P (2 m-tiles x 16 rows), padded

    const int tid = threadIdx.x, wave = tid >> 6, lane = tid & 63;
    const int quad = lane >> 4, ml = lane & 15;
    const int flat = blockIdx.x;
    const int qb = 15 - (flat >> 6);
    const int rest = flat & 63;
    const int bh = ((rest & 7) << 3) | (rest >> 3);
    const int q0 = qb * 128;
    const size_t base = (size_t)bh * (2048 * 64);
    const float NEG = -1.0e30f;

    bf16x8 qf[2][2];
#pragma unroll
    for (int mt = 0; mt < 2; mt++)
#pragma unroll
        for (int ks = 0; ks < 2; ks++)
            qf[mt][ks] = *(const bf16x8*)(Q + base + (size_t)(q0 + mt * 64 + wave * 16 + ml) * 64 + ks * 32 + quad * 8);

    f32x4 acc[2][4];
#pragma unroll
    for (int mt = 0; mt < 2; mt++)
#pragma unroll
        for (int nt = 0; nt < 4; nt++) acc[mt][nt] = (f32x4){0.f, 0.f, 0.f, 0.f};
    float l[2][4];
#pragma unroll
    for (int mt = 0; mt < 2; mt++)
#pragma unroll
        for (int r = 0; r < 4; r++) l[mt][r] = 0.f;

    const int ntj = qb + 1;
    for (int j = 0; j < ntj; j++){
        const int j0 = j * 128;
        __syncthreads();
#pragma unroll
        for (int i = 0; i < 4; i++){
            int ub = i * 256 + wave * 64;
            int u = ub + lane;
            int row = u >> 3, cg = (lane & 7) ^ (row & 7);
            glds16(K + base + (size_t)(j0 + row) * 64 + cg * 8, Ksm + ub * 8);
            int d = u >> 4, vg = (lane & 15) ^ (d & 15);
            glds16(Vt + base + (size_t)d * 2048 + j0 + vg * 8, Vsm + ub * 8);
        }
        __syncthreads();
        const bool lastj = (j == ntj - 1);

        // S = Q@K^T per 16-col tile; exp2 + P write immediately (s regs transient)
#pragma unroll
        for (int nt = 0; nt < 8; nt++){
            bf16x8 bk0 = *(const bf16x8*)&Ksm[(nt * 16 + ml) * 64 + ((quad)     ^ (ml & 7)) * 8];
            bf16x8 bk1 = *(const bf16x8*)&Ksm[(nt * 16 + ml) * 64 + ((4 + quad) ^ (ml & 7)) * 8];
            f32x4 z = {0.f, 0.f, 0.f, 0.f};
            f32x4 s0 = __builtin_amdgcn_mfma_f32_16x16x32_bf16(qf[0][0], bk0, z, 0, 0, 0);
            s0 = __builtin_amdgcn_mfma_f32_16x16x32_bf16(qf[0][1], bk1, s0, 0, 0, 0);
            f32x4 s1 = __builtin_amdgcn_mfma_f32_16x16x32_bf16(qf[1][0], bk0, z, 0, 0, 0);
            s1 = __builtin_amdgcn_mfma_f32_16x16x32_bf16(qf[1][1], bk1, s1, 0, 0, 0);
            if (lastj){
                int cl = nt * 16 + ml;
                int r0 = wave * 16 + quad * 4;
#pragma unroll
                for (int r = 0; r < 4; r++){
                    if (cl > r0 + r)      s0[r] = NEG;
                    if (cl > 64 + r0 + r) s1[r] = NEG;
                }
            }
#pragma unroll
            for (int r = 0; r < 4; r++){
                float p0 = exp2_fast(s0[r]); l[0][r] += p0;
                Psm[wave][(quad * 4 + r) * PS + nt * 16 + ml] = f2bf_t(p0);
                float p1 = exp2_fast(s1[r]); l[1][r] += p1;
                Psm[wave][(16 + quad * 4 + r) * PS + nt * 16 + ml] = f2bf_t(p1);
            }
        }
        // O += P @ V  (vf shared across both m-tiles)
#pragma unroll
        for (int ks = 0; ks < 4; ks++){
            bf16x8 pf0 = *(const bf16x8*)&Psm[wave][ml * PS + ks * 32 + quad * 8];
            bf16x8 pf1 = *(const bf16x8*)&Psm[wave][(16 + ml) * PS + ks * 32 + quad * 8];
#pragma unroll
            for (int nt = 0; nt < 4; nt++){
                bf16x8 vf = *(const bf16x8*)&Vsm[(nt * 16 + ml) * 128 + (((ks * 4 + quad) ^ ml) & 15) * 8];
                acc[0][nt] = __builtin_amdgcn_mfma_f32_16x16x32_bf16(pf0, vf, acc[0][nt], 0, 0, 0);
                acc[1][nt] = __builtin_amdgcn_mfma_f32_16x16x32_bf16(pf1, vf, acc[1][nt], 0, 0, 0);
            }
        }
    }
    // epilogue: l-reduction across the 16 ml lanes, then scale + store
    const int b = bh >> 4, h = bh & 15;
#pragma unroll
    for (int mt = 0; mt < 2; mt++){
        f32x4 inv;
#pragma unroll
        for (int r = 0; r < 4; r++){
            float t = l[mt][r];
            t += __shfl_xor(t, 1, 64);
            t += __shfl_xor(t, 2, 64);
            t += __shfl_xor(t, 4, 64);
            t += __shfl_xor(t, 8, 64);
            inv[r] = 1.0f / t;
        }
#pragma unroll
        for (int nt = 0; nt < 4; nt++)
#pragma unroll
            for (int r = 0; r < 4; r++){
                size_t row = (size_t)b * 2048 + q0 + mt * 64 + wave * 16 + quad * 4 + r;
                Y[row * 1024 + h * 64 + nt * 16 + ml] = f2bf(acc[mt][nt][r] * inv[r]);
            }
    }
}

extern "C" void kernel_launch(void* const* d_in, const int* in_sizes, int n_in,
                              void* d_out, int out_size, void* d_ws, size_t ws_size,
                              hipStream_t stream) {
    const void* x      = d_in[0];   // [8192][1024]  f32 or bf16 (probed at runtime)
    const void* W_attn = d_in[1];   // [1024][3072]
    const void* b_attn = d_in[2];   // [3072]
    const void* W_proj = d_in[3];   // [1024][1024]
    const void* b_proj = d_in[4];   // [1024]
    const u16* xprobe = (const u16*)x;

    // ws layout (64 MB, sequential reuse — verified R4-R7):
    //   [0, 8M)  elems: Q (pre-scaled); reused for Wt_proj after attention
    //   [8M,16M) elems: K
    //   [16M,24M)elems: Vt  [bh][d][t]
    //   [24M,32M)elems: Wt_attn (3M) -> Yw (8M)
    // x-as-bf16 lives in d_out as scratch until the final GEMM.
    u16* ws = (u16*)d_ws;
    u16* Qw = ws;
    u16* Kw = ws + 8u * 1024 * 1024;
    u16* Vw = ws + 16u * 1024 * 1024;
    u16* R  = ws + 24u * 1024 * 1024;
    u16* Wt_attn = R;
    u16* Yw      = R;
    u16* Wt_proj = Qw;
    u16* xb = (u16*)d_out;

    conv_x<<<4096, 256, 0, stream>>>(x, xb, xprobe);
    transposeW<<<dim3(48, 16), 256, 0, stream>>>(W_attn, Wt_attn, 1024, 3072, xprobe);
    gemm128<0><<<dim3(24, 64), 256, 0, stream>>>(
        xb, Wt_attn, b_attn, nullptr, Qw, Kw, Vw, xprobe, 8192, 3072, 1024);
    attn_kernel<<<1024, 256, 0, stream>>>(Qw, Kw, Vw, Yw);
    transposeW<<<dim3(16, 16), 256, 0, stream>>>(W_proj, Wt_proj, 1024, 1024, xprobe);
    gemm128<1><<<dim3(8, 64), 256, 0, stream>>>(
        Yw, Wt_proj, b_proj, d_out, nullptr, nullptr, nullptr, xprobe, 8192, 1024, 1024);
}